// Round 10
// baseline (181.127 us; speedup 1.0000x reference)
//
#include <hip/hip_runtime.h>
#include <hip/hip_fp16.h>

// Problem constants (DirectedGraphLayer): B=2, N=50000, FIN=128, FOUT=64, E=800000
#define Bc   2
#define Nn   50000
#define FINc 128
#define FOUTc 64
#define Mtot (Bc * Nn)          // 100000 combined (b,n) rows
#define CCOMB 128               // combined feature cols: [W cols 0..63 | W_self cols 0..63]
#define GB 1563                 // gemm tiles: ceil(100000/64)
#define GEMMB 391               // gemm-role blocks at 4 tiles/block: ceil(1563/4)
#define CAP 64                  // per-row edge capacity (P(Poisson16>64)~1e-17)

// binning parameters
#define NRNG   50               // rows per bucket
#define NBUCK  1000             // 50000 / 50 exactly
#define ABLK   256              // bin_a role blocks
#define ATHR   1024             // threads for fused + gather kernels (16 waves)
#define RECCAP 3200             // per-block stage chunk capacity (E/ABLK=3125)

typedef __bf16 bf16x8 __attribute__((ext_vector_type(8)));
typedef float  f32x4  __attribute__((ext_vector_type(4)));

static __device__ inline unsigned short f2bf(float f) {
    unsigned int u = __float_as_uint(f);
    u += 0x7fffu + ((u >> 16) & 1u);       // round-to-nearest-even
    return (unsigned short)(u >> 16);
}

// ---------------------------------------------------------------------------
// prep: 8 blocks pack [W|W_self] -> fragment-major bf16 (MFMA A-operand
// layout).
// ---------------------------------------------------------------------------
__global__ __launch_bounds__(256) void prep(
    const float* __restrict__ W, const float* __restrict__ Ws,
    unsigned short* __restrict__ Bp)
{
    const int idx = blockIdx.x * 256 + threadIdx.x;
    const int lane = idx & 63;
    const int kt   = (idx >> 6) & 3;
    const int nt   = idx >> 8;
    const int n    = nt * 16 + (lane & 15);
    const int k0   = kt * 32 + (lane >> 4) * 8;
    unsigned short o8[8];
#pragma unroll
    for (int j = 0; j < 8; ++j) {
        const int f = k0 + j;
        const float v = (n < 64) ? W[f * FOUTc + n] : Ws[f * FOUTc + (n - 64)];
        o8[j] = f2bf(v);
    }
    *(uint4*)&Bp[(size_t)idx * 8] = *(uint4*)o8;
}

// ---------------------------------------------------------------------------
// gemm_bina v2 (R10): fused independent roles with the R6 occupancy bug
// FIXED. R6's failure mechanism: 256-thr blocks + 31.7 KB LDS union -> 5
// blocks/CU = 20 waves. Now 1024-thr blocks: 2 blocks/CU is the THREAD cap
// (2048 = 32 waves = 100%), and 2 x ~38 KB LDS union costs nothing.
//   blocks 0..ABLK-1: bin_a (all co-resident at t=0, overlap gemm)
//   blocks ABLK.. : 4 gemm MFMA tiles per block (sub = threadIdx>>8)
// Bodies byte-identical to R9's separate kernels.
// ---------------------------------------------------------------------------
__global__ __launch_bounds__(1024) void gemm_bina(
    const float* __restrict__ x, const unsigned short* __restrict__ Bp,
    const float* __restrict__ bself,
    unsigned short* __restrict__ xrb, float* __restrict__ outp,
    const int* __restrict__ erow, const int* __restrict__ ecol,
    const float* __restrict__ evalv, unsigned int* __restrict__ cntm,
    unsigned int* __restrict__ ofsm, uint2* __restrict__ stage,
    int E, int ec)
{
    __shared__ unsigned int hist[1024];
    __shared__ unsigned int incl[1024];
    __shared__ unsigned int cur[NBUCK];
    __shared__ unsigned int recs[RECCAP * 2];

    const int b = blockIdx.x;

    if (b < ABLK) {
        // ---- bin_a role (atomic-free radix pass, 1024 threads) ----
        const int tid = threadIdx.x;
        const int ord = b;                     // 0..ABLK-1
        const int e0 = ord * ec;
        int e1 = e0 + ec; if (e1 > E) e1 = E;
        if (e1 - e0 > RECCAP) e1 = e0 + RECCAP;  // safety clamp
        const int tot = e1 - e0;

        hist[tid] = 0u;
        __syncthreads();

        // pass 1: histogram over row buckets (~3 edges/thread)
        for (int e = e0 + tid; e < e1; e += ATHR)
            atomicAdd(&hist[erow[e] / NRNG], 1u);
        __syncthreads();

        // inclusive Hillis-Steele scan over 1024 entries, one per thread
        incl[tid] = hist[tid];
        __syncthreads();
        for (int off = 1; off < 1024; off <<= 1) {
            const unsigned int a0 = (tid >= off) ? incl[tid - off] : 0u;
            __syncthreads();
            incl[tid] += a0;
            __syncthreads();
        }

        // init LDS cursors to exclusive offsets; emit cnt/ofs rows (coalesced)
        if (tid < NBUCK) {
            const unsigned int c = hist[tid];
            const unsigned int x0 = incl[tid] - c;
            cur[tid] = x0;
            cntm[(size_t)ord * NBUCK + tid] = c;
            ofsm[(size_t)ord * NBUCK + tid] = x0;
        }
        __syncthreads();

        // pass 2: re-read edges (L2-hot), regroup records by bucket in LDS
        for (int e = e0 + tid; e < e1; e += ATHR) {
            const int   r = erow[e];
            const int   c = ecol[e];
            const float v = evalv[e];
            const int  nb = r / NRNG;
            const unsigned int k = atomicAdd(&cur[nb], 1u);
            recs[2 * k]     = ((unsigned int)__half_as_ushort(__float2half(v)) << 17) |
                              (unsigned int)c;
            recs[2 * k + 1] = (unsigned int)(r - nb * NRNG);
        }
        __syncthreads();

        // pass 3: contiguous coalesced dump into private stage chunk
        uint2* __restrict__ chunk = &stage[(size_t)ord * RECCAP];
        for (int j = tid; j < tot; j += ATHR)
            chunk[j] = make_uint2(recs[2 * j], recs[2 * j + 1]);
        return;
    }

    // ---- gemm role: 4 independent 64-row MFMA tiles per block ----
    const int sub = threadIdx.x >> 8;        // 0..3
    const int t   = threadIdx.x & 255;
    const int gb  = (b - ABLK) * 4 + sub;
    if (gb >= GB) return;

    const int lane = t & 63;
    const int quad = lane >> 4;
    const int mbase = gb * 64 + (t >> 6) * 16;

    const int mrow   = mbase + (lane & 15);
    const int mclamp = (mrow < Mtot) ? mrow : (Mtot - 1);
    const float* __restrict__ xrow = &x[(size_t)mclamp * FINc + quad * 8];

    float4 xv[8];
#pragma unroll
    for (int kt = 0; kt < 4; ++kt) {
        xv[2 * kt]     = *(const float4*)&xrow[kt * 32];
        xv[2 * kt + 1] = *(const float4*)&xrow[kt * 32 + 4];
    }

    f32x4 acc[8] = {};

#pragma unroll
    for (int kt = 0; kt < 4; ++kt) {
        const float4 xa = xv[2 * kt];
        const float4 xb = xv[2 * kt + 1];
        bf16x8 bf;                       // B operand: B[k][m], m=lane&15
        bf[0] = (__bf16)xa.x; bf[1] = (__bf16)xa.y;
        bf[2] = (__bf16)xa.z; bf[3] = (__bf16)xa.w;
        bf[4] = (__bf16)xb.x; bf[5] = (__bf16)xb.y;
        bf[6] = (__bf16)xb.z; bf[7] = (__bf16)xb.w;

        const bf16x8* __restrict__ abase =
            (const bf16x8*)&Bp[(size_t)(kt * 64 + lane) * 8];
#pragma unroll
        for (int nt = 0; nt < 8; ++nt) {
            const bf16x8 af = abase[nt * 4 * 64];   // entry (nt*4+kt)*64+lane
            acc[nt] = __builtin_amdgcn_mfma_f32_16x16x32_bf16(af, bf, acc[nt], 0, 0, 0);
        }
    }

    const int m = mbase + (lane & 15);
    if (m < Mtot) {
        const int bb = (m >= Nn) ? 1 : 0;
        const int n = m - bb * Nn;
        unsigned short* __restrict__ xp = &xrb[(size_t)n * CCOMB + bb * FOUTc];
        const int cq = quad * 4;
#pragma unroll
        for (int nt = 0; nt < 4; ++nt) {
            const int c = nt * 16 + cq;
            unsigned short h[4];
            h[0] = f2bf(acc[nt][0]); h[1] = f2bf(acc[nt][1]);
            h[2] = f2bf(acc[nt][2]); h[3] = f2bf(acc[nt][3]);
            *(uint2*)&xp[c] = *(uint2*)h;           // 8 B store
        }
        float* __restrict__ op = &outp[(size_t)m * FOUTc];
#pragma unroll
        for (int nt = 4; nt < 8; ++nt) {
            const int o = (nt - 4) * 16 + cq;
            const float4 b4 = *(const float4*)&bself[o];
            float4 v;
            v.x = acc[nt][0] + b4.x; v.y = acc[nt][1] + b4.y;
            v.z = acc[nt][2] + b4.z; v.w = acc[nt][3] + b4.w;
            *(float4*)&op[o] = v;                   // 16 B store, line-dense
        }
    }
}

// ---------------------------------------------------------------------------
// bin_gather: merged bin_b + row_gather (unchanged from R9). One block per
// 50-row bucket, 1024 threads. Phase 1 (threads 0..255): pull chunk runs
// into per-row CAP-64 lists in LDS. Phase 2 (16 waves): per-wave row-half
// gather; edge words from LDS; fused finalize out = relu(self_pre + agg).
// ---------------------------------------------------------------------------
#define GATHP(W, PRED, ACC)                                                   \
    {                                                                         \
        const unsigned int w = (W);                                           \
        unsigned int col = w & 0x1FFFFu;                                      \
        col = (col < Nn) ? col : 0u;       /* clamp speculative garbage */    \
        const float vv = (PRED) ? __half2float(__ushort_as_half(              \
                             (unsigned short)(w >> 17))) : 0.0f;              \
        const uint4 raw = *(const uint4*)&xrb[(size_t)col * CCOMB + c0];      \
        ACC[0] = fmaf(vv, __uint_as_float(raw.x << 16),         ACC[0]);      \
        ACC[1] = fmaf(vv, __uint_as_float(raw.x & 0xffff0000u), ACC[1]);      \
        ACC[2] = fmaf(vv, __uint_as_float(raw.y << 16),         ACC[2]);      \
        ACC[3] = fmaf(vv, __uint_as_float(raw.y & 0xffff0000u), ACC[3]);      \
        ACC[4] = fmaf(vv, __uint_as_float(raw.z << 16),         ACC[4]);      \
        ACC[5] = fmaf(vv, __uint_as_float(raw.z & 0xffff0000u), ACC[5]);      \
        ACC[6] = fmaf(vv, __uint_as_float(raw.w << 16),         ACC[6]);      \
        ACC[7] = fmaf(vv, __uint_as_float(raw.w & 0xffff0000u), ACC[7]);      \
    }

__global__ __launch_bounds__(1024) void bin_gather(
    const unsigned int* __restrict__ cntm, const unsigned int* __restrict__ ofsm,
    const uint2* __restrict__ stage, const unsigned short* __restrict__ xrb,
    float* __restrict__ outp)
{
    __shared__ unsigned int lists[NRNG * CAP];   // 12.8 KB
    __shared__ unsigned int lcnt[NRNG];

    const int tid = threadIdx.x;
    const int nb  = blockIdx.x;                  // 0..NBUCK-1
    const int row0 = nb * NRNG;

    if (tid < NRNG) lcnt[tid] = 0u;
    __syncthreads();

    // phase 1: thread t <-> bin_a chunk t (t < ABLK); mean run ~3 records
    if (tid < ABLK) {
        const unsigned int c = cntm[(size_t)tid * NBUCK + nb];
        const unsigned int o = ofsm[(size_t)tid * NBUCK + nb];
        const uint2* __restrict__ run = &stage[(size_t)tid * RECCAP + o];
        for (unsigned int j = 0; j < c; ++j) {
            const uint2 rec = run[j];
            const int rl = (int)rec.y;           // 0..NRNG-1
            const unsigned int k = atomicAdd(&lcnt[rl], 1u);
            if (k < CAP) lists[(rl << 6) + k] = rec.x;
        }
    }
    __syncthreads();

    // phase 2: 16 waves sweep 100 row-half tasks
    const int wid  = tid >> 6;
    const int lane = tid & 63;
    const int slot = lane >> 3;                  // edge slot 0..7

    for (int task = wid; task < NRNG * 2; task += 16) {
        const int rl = task >> 1;
        const int h  = task & 1;
        const int c0 = h * 64 + (lane & 7) * 8;  // 8 combined cols per lane
        const int rbase = rl << 6;

        const int kc = min((int)lcnt[rl], CAP);
        const unsigned int u0 = lists[rbase + slot];
        const unsigned int u1 = lists[rbase + 8 + slot];

        float aA[8] = {0.f, 0.f, 0.f, 0.f, 0.f, 0.f, 0.f, 0.f};

        GATHP(u0, slot < kc,     aA);
        GATHP(u1, slot + 8 < kc, aA);

        for (int e = 16 + slot; e < kc; e += 8) {
            const unsigned int u = lists[rbase + e];
            GATHP(u, true, aA);
        }

#pragma unroll
        for (int i = 0; i < 8; ++i) {
            aA[i] += __shfl_down(aA[i], 8);
            aA[i] += __shfl_down(aA[i], 16);
            aA[i] += __shfl_down(aA[i], 32);
        }

        if (lane < 8) {
            const size_t m = (size_t)h * Nn + (row0 + rl);
            const int o = lane * 8;              // feature offset within 64
            float* __restrict__ op = &outp[m * FOUTc + o];
            float4 s0 = *(float4*)&op[0];
            float4 s1 = *(float4*)&op[4];
            s0.x = fmaxf(s0.x + aA[0], 0.0f); s0.y = fmaxf(s0.y + aA[1], 0.0f);
            s0.z = fmaxf(s0.z + aA[2], 0.0f); s0.w = fmaxf(s0.w + aA[3], 0.0f);
            s1.x = fmaxf(s1.x + aA[4], 0.0f); s1.y = fmaxf(s1.y + aA[5], 0.0f);
            s1.z = fmaxf(s1.z + aA[6], 0.0f); s1.w = fmaxf(s1.w + aA[7], 0.0f);
            *(float4*)&op[0] = s0;
            *(float4*)&op[4] = s1;
        }
    }
}

extern "C" void kernel_launch(void* const* d_in, const int* in_sizes, int n_in,
                              void* d_out, int out_size, void* d_ws, size_t ws_size,
                              hipStream_t stream)
{
    const float* x    = (const float*)d_in[0];
    const float* W    = (const float*)d_in[1];
    const float* Ws   = (const float*)d_in[2];
    const float* bs   = (const float*)d_in[3];
    const int*   erow = (const int*)d_in[4];
    const int*   ecol = (const int*)d_in[5];
    const float* eval = (const float*)d_in[6];
    float* outp = (float*)d_out;
    const int E = in_sizes[4];

    // workspace layout (~21.4 MB total)
    unsigned short* xrb = (unsigned short*)d_ws;                      // 12.8 MB
    unsigned short* Bp  = xrb + (size_t)Nn * CCOMB;                   // 32 KB
    unsigned int*   cntm = (unsigned int*)(Bp + 16384);               // 1.0 MB
    unsigned int*   ofsm = cntm + (size_t)ABLK * NBUCK;               // 1.0 MB
    uint2*          stage = (uint2*)(ofsm + (size_t)ABLK * NBUCK);    // 6.55 MB

    const int ec = (E + ABLK - 1) / ABLK;

    // 1. pack weights
    prep<<<8, 256, 0, stream>>>(W, Ws, Bp);

    // 2. fused: bin_a (blocks 0..255, co-resident from t=0) + gemm (4 tiles/blk)
    gemm_bina<<<ABLK + GEMMB, ATHR, 0, stream>>>(x, Bp, bs, xrb, outp,
                                                 erow, ecol, eval,
                                                 cntm, ofsm, stage, E, ec);

    // 3. merged: per-bucket LDS lists + gather-reduce + finalize
    bin_gather<<<NBUCK, ATHR, 0, stream>>>(cntm, ofsm, stage, xrb, outp);
}

// Round 11
// 174.832 us; speedup vs baseline: 1.0360x; 1.0360x over previous
//
#include <hip/hip_runtime.h>
#include <hip/hip_fp16.h>

// Problem constants (DirectedGraphLayer): B=2, N=50000, FIN=128, FOUT=64, E=800000
#define Bc   2
#define Nn   50000
#define FINc 128
#define FOUTc 64
#define Mtot (Bc * Nn)          // 100000 combined (b,n) rows
#define CCOMB 128               // combined feature cols: [W cols 0..63 | W_self cols 0..63]
#define GB 1563                 // gemm tiles: ceil(100000/64)
#define CAP 64                  // per-row edge capacity (P(Poisson16>64)~1e-17)

// binning parameters
#define NRNG   50               // rows per bucket
#define NBUCK  1000             // 50000 / 50 exactly
#define ABLK   256              // bin_a blocks (1 per CU)
#define ATHR   1024             // bin_a/bin_gather threads (16 waves)
#define RECCAP 3200             // per-block stage chunk capacity (E/ABLK=3125)

typedef __bf16 bf16x8 __attribute__((ext_vector_type(8)));
typedef float  f32x4  __attribute__((ext_vector_type(4)));

static __device__ inline unsigned short f2bf(float f) {
    unsigned int u = __float_as_uint(f);
    u += 0x7fffu + ((u >> 16) & 1u);       // round-to-nearest-even
    return (unsigned short)(u >> 16);
}

// ---------------------------------------------------------------------------
// prep: 8 blocks pack [W|W_self] -> fragment-major bf16 (MFMA A-operand
// layout).
// ---------------------------------------------------------------------------
__global__ __launch_bounds__(256) void prep(
    const float* __restrict__ W, const float* __restrict__ Ws,
    unsigned short* __restrict__ Bp)
{
    const int idx = blockIdx.x * 256 + threadIdx.x;
    const int lane = idx & 63;
    const int kt   = (idx >> 6) & 3;
    const int nt   = idx >> 8;
    const int n    = nt * 16 + (lane & 15);
    const int k0   = kt * 32 + (lane >> 4) * 8;
    unsigned short o8[8];
#pragma unroll
    for (int j = 0; j < 8; ++j) {
        const int f = k0 + j;
        const float v = (n < 64) ? W[f * FOUTc + n] : Ws[f * FOUTc + (n - 64)];
        o8[j] = f2bf(v);
    }
    *(uint4*)&Bp[(size_t)idx * 8] = *(uint4*)o8;
}

// ---------------------------------------------------------------------------
// gemm: one 64-row MFMA tile per block; zero LDS (full occupancy).
// (R10 post-mortem: in-kernel role fusion with bin_a was neutral in 4
// separate attempts with 3 distinct diagnosed mechanisms -> abandoned.)
//   cols 0..63  -> xrb (bf16, (N, B*64) layout)
//   cols 64..127-> outp pre-ReLU self term (+bias, f32)
// ---------------------------------------------------------------------------
__global__ __launch_bounds__(256) void gemm(
    const float* __restrict__ x, const unsigned short* __restrict__ Bp,
    const float* __restrict__ bself,
    unsigned short* __restrict__ xrb, float* __restrict__ outp)
{
    const int gb   = blockIdx.x;             // 0..GB-1
    const int lane = threadIdx.x & 63;
    const int quad = lane >> 4;
    const int mbase = gb * 64 + (threadIdx.x >> 6) * 16;

    const int mrow   = mbase + (lane & 15);
    const int mclamp = (mrow < Mtot) ? mrow : (Mtot - 1);
    const float* __restrict__ xrow = &x[(size_t)mclamp * FINc + quad * 8];

    float4 xv[8];
#pragma unroll
    for (int kt = 0; kt < 4; ++kt) {
        xv[2 * kt]     = *(const float4*)&xrow[kt * 32];
        xv[2 * kt + 1] = *(const float4*)&xrow[kt * 32 + 4];
    }

    f32x4 acc[8] = {};

#pragma unroll
    for (int kt = 0; kt < 4; ++kt) {
        const float4 xa = xv[2 * kt];
        const float4 xb = xv[2 * kt + 1];
        bf16x8 bf;                       // B operand: B[k][m], m=lane&15
        bf[0] = (__bf16)xa.x; bf[1] = (__bf16)xa.y;
        bf[2] = (__bf16)xa.z; bf[3] = (__bf16)xa.w;
        bf[4] = (__bf16)xb.x; bf[5] = (__bf16)xb.y;
        bf[6] = (__bf16)xb.z; bf[7] = (__bf16)xb.w;

        const bf16x8* __restrict__ abase =
            (const bf16x8*)&Bp[(size_t)(kt * 64 + lane) * 8];
#pragma unroll
        for (int nt = 0; nt < 8; ++nt) {
            const bf16x8 af = abase[nt * 4 * 64];   // entry (nt*4+kt)*64+lane
            acc[nt] = __builtin_amdgcn_mfma_f32_16x16x32_bf16(af, bf, acc[nt], 0, 0, 0);
        }
    }

    const int m = mbase + (lane & 15);
    if (m < Mtot) {
        const int bb = (m >= Nn) ? 1 : 0;
        const int n = m - bb * Nn;
        unsigned short* __restrict__ xp = &xrb[(size_t)n * CCOMB + bb * FOUTc];
        const int cq = quad * 4;
#pragma unroll
        for (int nt = 0; nt < 4; ++nt) {
            const int c = nt * 16 + cq;
            unsigned short h[4];
            h[0] = f2bf(acc[nt][0]); h[1] = f2bf(acc[nt][1]);
            h[2] = f2bf(acc[nt][2]); h[3] = f2bf(acc[nt][3]);
            *(uint2*)&xp[c] = *(uint2*)h;           // 8 B store
        }
        float* __restrict__ op = &outp[(size_t)m * FOUTc];
#pragma unroll
        for (int nt = 4; nt < 8; ++nt) {
            const int o = (nt - 4) * 16 + cq;
            const float4 b4 = *(const float4*)&bself[o];
            float4 v;
            v.x = acc[nt][0] + b4.x; v.y = acc[nt][1] + b4.y;
            v.z = acc[nt][2] + b4.z; v.w = acc[nt][3] + b4.w;
            *(float4*)&op[o] = v;                   // 16 B store, line-dense
        }
    }
}

// ---------------------------------------------------------------------------
// bin_a: atomic-free radix pass, 1024 threads (16 waves/CU). 50-row buckets
// (NBUCK=1000). LDS histogram + 1024-wide scan; records regrouped by bucket
// in LDS; contiguous dump into private stage chunk; cnt/ofs rows coalesced.
// ---------------------------------------------------------------------------
__global__ __launch_bounds__(1024) void bin_a(
    const int* __restrict__ erow, const int* __restrict__ ecol,
    const float* __restrict__ evalv, unsigned int* __restrict__ cntm,
    unsigned int* __restrict__ ofsm, uint2* __restrict__ stage,
    int E, int ec)
{
    __shared__ unsigned int hist[1024];    // 1000 buckets, padded
    __shared__ unsigned int incl[1024];
    __shared__ unsigned int cur[NBUCK];
    __shared__ unsigned int recs[RECCAP * 2];

    const int tid = threadIdx.x;
    const int ord = blockIdx.x;            // 0..ABLK-1
    const int e0 = ord * ec;
    int e1 = e0 + ec; if (e1 > E) e1 = E;
    if (e1 - e0 > RECCAP) e1 = e0 + RECCAP;  // safety clamp
    const int tot = e1 - e0;

    hist[tid] = 0u;
    __syncthreads();

    // pass 1: histogram over row buckets (~3 edges/thread)
    for (int e = e0 + tid; e < e1; e += ATHR)
        atomicAdd(&hist[erow[e] / NRNG], 1u);
    __syncthreads();

    // inclusive Hillis-Steele scan over 1024 entries, one per thread
    incl[tid] = hist[tid];
    __syncthreads();
    for (int off = 1; off < 1024; off <<= 1) {
        const unsigned int a0 = (tid >= off) ? incl[tid - off] : 0u;
        __syncthreads();
        incl[tid] += a0;
        __syncthreads();
    }

    // init LDS cursors to exclusive offsets; emit cnt/ofs rows (coalesced)
    if (tid < NBUCK) {
        const unsigned int c = hist[tid];
        const unsigned int x0 = incl[tid] - c;
        cur[tid] = x0;
        cntm[(size_t)ord * NBUCK + tid] = c;
        ofsm[(size_t)ord * NBUCK + tid] = x0;
    }
    __syncthreads();

    // pass 2: re-read edges (L2-hot), regroup records by bucket in LDS
    for (int e = e0 + tid; e < e1; e += ATHR) {
        const int   r = erow[e];
        const int   c = ecol[e];
        const float v = evalv[e];
        const int  nb = r / NRNG;
        const unsigned int k = atomicAdd(&cur[nb], 1u);
        recs[2 * k]     = ((unsigned int)__half_as_ushort(__float2half(v)) << 17) |
                          (unsigned int)c;
        recs[2 * k + 1] = (unsigned int)(r - nb * NRNG);
    }
    __syncthreads();

    // pass 3: contiguous coalesced dump into private stage chunk
    uint2* __restrict__ chunk = &stage[(size_t)ord * RECCAP];
    for (int j = tid; j < tot; j += ATHR)
        chunk[j] = make_uint2(recs[2 * j], recs[2 * j + 1]);
}

// ---------------------------------------------------------------------------
// bin_gather v2 (R11): two latency fixes on the dominant dispatch.
//  1. phase 1 now uses ALL 1024 threads (4 threads per chunk, record stride
//     4) instead of 256 threads walking ~3 dependent loads each while 12
//     waves idled at the barrier. List order was already nondeterministic
//     (LDS atomics), so numerics class is unchanged.
//  2. phase 2 merges the (row,h=0)/(row,h=1) task pair: they share the SAME
//     edge list, kc, and LDS reads — only the column offset differs. One
//     row-task now issues paired rA/rB xrb loads per edge -> 2x outstanding
//     loads per wave (the lever for a latency-bound gather), half the LDS
//     list reads, no divergence (kc is wave-uniform).
// Fused finalize: out = relu(self_pre + agg) for both batch halves.
// ---------------------------------------------------------------------------
#define GATHP2(W, PRED, A, B)                                                 \
    {                                                                         \
        const unsigned int w = (W);                                           \
        unsigned int col = w & 0x1FFFFu;                                      \
        col = (col < Nn) ? col : 0u;       /* clamp speculative garbage */    \
        const float vv = (PRED) ? __half2float(__ushort_as_half(              \
                             (unsigned short)(w >> 17))) : 0.0f;              \
        const unsigned short* __restrict__ rp = &xrb[(size_t)col * CCOMB];    \
        const uint4 rA = *(const uint4*)&rp[c0A];                             \
        const uint4 rB = *(const uint4*)&rp[c0B];                             \
        A[0] = fmaf(vv, __uint_as_float(rA.x << 16),         A[0]);           \
        A[1] = fmaf(vv, __uint_as_float(rA.x & 0xffff0000u), A[1]);           \
        A[2] = fmaf(vv, __uint_as_float(rA.y << 16),         A[2]);           \
        A[3] = fmaf(vv, __uint_as_float(rA.y & 0xffff0000u), A[3]);           \
        A[4] = fmaf(vv, __uint_as_float(rA.z << 16),         A[4]);           \
        A[5] = fmaf(vv, __uint_as_float(rA.z & 0xffff0000u), A[5]);           \
        A[6] = fmaf(vv, __uint_as_float(rA.w << 16),         A[6]);           \
        A[7] = fmaf(vv, __uint_as_float(rA.w & 0xffff0000u), A[7]);           \
        B[0] = fmaf(vv, __uint_as_float(rB.x << 16),         B[0]);           \
        B[1] = fmaf(vv, __uint_as_float(rB.x & 0xffff0000u), B[1]);           \
        B[2] = fmaf(vv, __uint_as_float(rB.y << 16),         B[2]);           \
        B[3] = fmaf(vv, __uint_as_float(rB.y & 0xffff0000u), B[3]);           \
        B[4] = fmaf(vv, __uint_as_float(rB.z << 16),         B[4]);           \
        B[5] = fmaf(vv, __uint_as_float(rB.z & 0xffff0000u), B[5]);           \
        B[6] = fmaf(vv, __uint_as_float(rB.w << 16),         B[6]);           \
        B[7] = fmaf(vv, __uint_as_float(rB.w & 0xffff0000u), B[7]);           \
    }

__global__ __launch_bounds__(1024) void bin_gather(
    const unsigned int* __restrict__ cntm, const unsigned int* __restrict__ ofsm,
    const uint2* __restrict__ stage, const unsigned short* __restrict__ xrb,
    float* __restrict__ outp)
{
    __shared__ unsigned int lists[NRNG * CAP];   // 12.8 KB
    __shared__ unsigned int lcnt[NRNG];

    const int tid = threadIdx.x;
    const int nb  = blockIdx.x;                  // 0..NBUCK-1
    const int row0 = nb * NRNG;

    if (tid < NRNG) lcnt[tid] = 0u;
    __syncthreads();

    // phase 1: 4 threads per chunk (chunk = tid&255, record stride 4)
    {
        const int ch = tid & 255;
        const int j0 = tid >> 8;                 // 0..3
        const unsigned int c = cntm[(size_t)ch * NBUCK + nb];
        const unsigned int o = ofsm[(size_t)ch * NBUCK + nb];
        const uint2* __restrict__ run = &stage[(size_t)ch * RECCAP + o];
        for (unsigned int j = (unsigned int)j0; j < c; j += 4) {
            const uint2 rec = run[j];
            const int rl = (int)rec.y;           // 0..NRNG-1
            const unsigned int k = atomicAdd(&lcnt[rl], 1u);
            if (k < CAP) lists[(rl << 6) + k] = rec.x;
        }
    }
    __syncthreads();

    // phase 2: 16 waves sweep 50 full-row tasks (both batch halves together)
    const int wid  = tid >> 6;
    const int lane = tid & 63;
    const int slot = lane >> 3;                  // edge slot 0..7
    const int c0A  = (lane & 7) * 8;             // batch0 cols
    const int c0B  = 64 + c0A;                   // batch1 cols

    for (int rl = wid; rl < NRNG; rl += 16) {
        const int rbase = rl << 6;
        const int kc = min((int)lcnt[rl], CAP);  // wave-uniform
        const unsigned int u0 = lists[rbase + slot];
        const unsigned int u1 = lists[rbase + 8 + slot];

        float aA[8] = {0.f, 0.f, 0.f, 0.f, 0.f, 0.f, 0.f, 0.f};
        float aB[8] = {0.f, 0.f, 0.f, 0.f, 0.f, 0.f, 0.f, 0.f};

        GATHP2(u0, slot < kc,     aA, aB);
        GATHP2(u1, slot + 8 < kc, aA, aB);

        for (int e = 16 + slot; e < kc; e += 8) {
            const unsigned int u = lists[rbase + e];
            GATHP2(u, true, aA, aB);
        }

#pragma unroll
        for (int i = 0; i < 8; ++i) {
            aA[i] += __shfl_down(aA[i], 8);
            aA[i] += __shfl_down(aA[i], 16);
            aA[i] += __shfl_down(aA[i], 32);
            aB[i] += __shfl_down(aB[i], 8);
            aB[i] += __shfl_down(aB[i], 16);
            aB[i] += __shfl_down(aB[i], 32);
        }

        if (lane < 8) {
            const int o = lane * 8;              // feature offset within 64
            float* __restrict__ op0 = &outp[(size_t)(row0 + rl) * FOUTc + o];
            float* __restrict__ op1 = &outp[((size_t)Nn + row0 + rl) * FOUTc + o];
            float4 s0 = *(float4*)&op0[0];
            float4 s1 = *(float4*)&op0[4];
            s0.x = fmaxf(s0.x + aA[0], 0.0f); s0.y = fmaxf(s0.y + aA[1], 0.0f);
            s0.z = fmaxf(s0.z + aA[2], 0.0f); s0.w = fmaxf(s0.w + aA[3], 0.0f);
            s1.x = fmaxf(s1.x + aA[4], 0.0f); s1.y = fmaxf(s1.y + aA[5], 0.0f);
            s1.z = fmaxf(s1.z + aA[6], 0.0f); s1.w = fmaxf(s1.w + aA[7], 0.0f);
            *(float4*)&op0[0] = s0;
            *(float4*)&op0[4] = s1;
            float4 t0 = *(float4*)&op1[0];
            float4 t1 = *(float4*)&op1[4];
            t0.x = fmaxf(t0.x + aB[0], 0.0f); t0.y = fmaxf(t0.y + aB[1], 0.0f);
            t0.z = fmaxf(t0.z + aB[2], 0.0f); t0.w = fmaxf(t0.w + aB[3], 0.0f);
            t1.x = fmaxf(t1.x + aB[4], 0.0f); t1.y = fmaxf(t1.y + aB[5], 0.0f);
            t1.z = fmaxf(t1.z + aB[6], 0.0f); t1.w = fmaxf(t1.w + aB[7], 0.0f);
            *(float4*)&op1[0] = t0;
            *(float4*)&op1[4] = t1;
        }
    }
}

extern "C" void kernel_launch(void* const* d_in, const int* in_sizes, int n_in,
                              void* d_out, int out_size, void* d_ws, size_t ws_size,
                              hipStream_t stream)
{
    const float* x    = (const float*)d_in[0];
    const float* W    = (const float*)d_in[1];
    const float* Ws   = (const float*)d_in[2];
    const float* bs   = (const float*)d_in[3];
    const int*   erow = (const int*)d_in[4];
    const int*   ecol = (const int*)d_in[5];
    const float* eval = (const float*)d_in[6];
    float* outp = (float*)d_out;
    const int E = in_sizes[4];

    // workspace layout (~21.4 MB total)
    unsigned short* xrb = (unsigned short*)d_ws;                      // 12.8 MB
    unsigned short* Bp  = xrb + (size_t)Nn * CCOMB;                   // 32 KB
    unsigned int*   cntm = (unsigned int*)(Bp + 16384);               // 1.0 MB
    unsigned int*   ofsm = cntm + (size_t)ABLK * NBUCK;               // 1.0 MB
    uint2*          stage = (uint2*)(ofsm + (size_t)ABLK * NBUCK);    // 6.55 MB

    const int ec = (E + ABLK - 1) / ABLK;

    // 1. pack weights
    prep<<<8, 256, 0, stream>>>(W, Ws, Bp);

    // 2. dense MFMA transform + self term (no LDS -> full occupancy)
    gemm<<<GB, 256, 0, stream>>>(x, Bp, bs, xrb, outp);

    // 3. atomic-free edge binning pass A (256 blocks x 1024 thr)
    bin_a<<<ABLK, ATHR, 0, stream>>>(erow, ecol, eval, cntm, ofsm, stage, E, ec);

    // 4. merged: per-bucket LDS lists + full-row gather-reduce + finalize
    bin_gather<<<NBUCK, ATHR, 0, stream>>>(cntm, ofsm, stage, xrb, outp);
}